// Round 4
// baseline (6297.794 us; speedup 1.0000x reference)
//
#include <hip/hip_runtime.h>
#include <hip/hip_bf16.h>
#include <cstdint>

#define TT 1024
#define BB 64
#define DD 1024
#define HH 30
#define G4 120

#define NPROD 64    // producer blocks (GEMM), t-striped rounds
#define NROUND 8    // tiles per producer block
#define NCBLK 8     // consumer blocks, 8 batch-pairs (16 waves) each
#define GBLK 16     // tiles per flag group => 32 timesteps per group
#define GDONE 64    // per-group completion count: 16 tiles x 4 producer waves
#define NGRP 32     // number of flag groups

typedef __attribute__((ext_vector_type(8))) short short8;
typedef __attribute__((ext_vector_type(4))) float float4v;

// ---------------------------------------------------------------------------
__device__ __forceinline__ float frcp(float x) { return __builtin_amdgcn_rcpf(x); }
__device__ __forceinline__ float fsig(float x) { return frcp(1.0f + __expf(-x)); }
__device__ __forceinline__ float ftan(float x) {
    return 2.0f * frcp(1.0f + __expf(-2.0f * x)) - 1.0f;
}
__device__ __forceinline__ float bcast(float v, int l) {
    return __int_as_float(__builtin_amdgcn_readlane(__float_as_int(v), l));
}
__device__ __forceinline__ unsigned short bf16_rne(float f) {
    unsigned u = __float_as_uint(f);
    return (unsigned short)((u + 0x7FFFu + ((u >> 16) & 1u)) >> 16);
}
// Raw workgroup barrier: orders LDS ops but does NOT drain vmcnt — in-flight
// global prefetches/stores survive across it.
__device__ __forceinline__ void barrier_lds_only() {
    asm volatile("s_waitcnt lgkmcnt(0)\n\ts_barrier" ::: "memory");
}

// ---------------------------------------------------------------------------
// Prep: pack W_ih0 into MFMA B-fragment order (split bf16 hi/lo), combine
// layer-0 biases, zero the producer-consumer flags.
__global__ void prep_kernel(const float* __restrict__ Wih0,
                            const float* __restrict__ bih0,
                            const float* __restrict__ bhh0,
                            unsigned short* __restrict__ Bhi,
                            unsigned short* __restrict__ Blo,
                            float* __restrict__ bias0,
                            unsigned* __restrict__ cnt) {
    int idx = blockIdx.x * 256 + threadIdx.x;   // 0..16383
    int l  = idx & 63;
    int kc = (idx >> 6) & 31;
    int nt = idx >> 11;
    int n = nt * 16 + (l & 15);
    int kb = kc * 32 + (l >> 4) * 8;
    size_t o = (size_t)idx * 8;
#pragma unroll
    for (int j = 0; j < 8; ++j) {
        float wv = (n < G4) ? Wih0[(size_t)n * DD + kb + j] : 0.0f;
        unsigned short hi = bf16_rne(wv);
        float fhi = __uint_as_float((unsigned)hi << 16);
        unsigned short lo = bf16_rne(wv - fhi);
        Bhi[o + j] = hi;
        Blo[o + j] = lo;
    }
    if (idx < 128) bias0[idx] = (idx < G4) ? (bih0[idx] + bhh0[idx]) : 0.0f;
    if (idx < NGRP) cnt[idx] = 0u;
}

// ---------------------------------------------------------------------------
// Fused producer-consumer kernel, 1024-thread blocks.
//  blocks [0, NPROD): GEMM producers. Only waves 0-3 work (waves 4-15 exit
//      immediately; no producer barrier — each wave does vmcnt(0) + its own
//      release-add, so a flag group completes at GDONE=64).
//  blocks [NPROD, NPROD+NCBLK): consumers. 16 waves = 8 independent
//      batch-pairs running the two-wave-skew recurrence -> 4 waves/SIMD so
//      independent chains hide each other's dependent-op latency.
// No deadlock: producers never wait and have no barriers; consumer barriers
// include all 16 live waves.
__global__ __launch_bounds__(1024) void fused_fwd(
    const float* __restrict__ x, const unsigned short* __restrict__ Bhi,
    const unsigned short* __restrict__ Blo, const float* __restrict__ bias0,
    float* __restrict__ xgp, const float* __restrict__ Whh0,
    const float* __restrict__ Wih1, const float* __restrict__ Whh1,
    const float* __restrict__ bih1, const float* __restrict__ bhh1,
    float* __restrict__ h2buf, unsigned* __restrict__ cnt) {

    __shared__ float2 pg[8][2][64];   // per-pair layer-1 partial-gate ring
    const int tid = threadIdx.x;

    if (blockIdx.x < NPROD) {
        if (tid >= 256) return;       // waves 4-15 idle in producer blocks
        // ================= producer: xg = x @ Wih0^T (+bias) =================
        const int pb = blockIdx.x;
        const int w = tid >> 6;
        const int l = tid & 63;
        const int lm = l & 15, lq = l >> 4;

        for (int r = 0; r < NROUND; ++r) {
            const int tile = r * NPROD + pb;          // 0..511, t-pair index
            const int r0 = tile * 128 + w * 32;

            float4v acc[2][8];
#pragma unroll
            for (int mt = 0; mt < 2; ++mt)
#pragma unroll
                for (int nt = 0; nt < 8; ++nt) acc[mt][nt] = (float4v)0.0f;

            const float* aptr[2];
            aptr[0] = x + (size_t)(r0 + lm) * DD + lq * 8;
            aptr[1] = x + (size_t)(r0 + 16 + lm) * DD + lq * 8;

            float4 pa[2][2];
#pragma unroll
            for (int mt = 0; mt < 2; ++mt) {
                pa[mt][0] = *(const float4*)(aptr[mt]);
                pa[mt][1] = *(const float4*)(aptr[mt] + 4);
            }

            for (int kc = 0; kc < 32; ++kc) {
                short8 ahi[2], alo[2];
#pragma unroll
                for (int mt = 0; mt < 2; ++mt) {
                    float f[8] = {pa[mt][0].x, pa[mt][0].y, pa[mt][0].z, pa[mt][0].w,
                                  pa[mt][1].x, pa[mt][1].y, pa[mt][1].z, pa[mt][1].w};
#pragma unroll
                    for (int i = 0; i < 8; ++i) {
                        unsigned ub = __float_as_uint(f[i]);
                        ahi[mt][i] = (short)(ub >> 16);
                        float fr = f[i] - __uint_as_float(ub & 0xFFFF0000u);
                        alo[mt][i] = (short)(__float_as_uint(fr) >> 16);
                    }
                }
                if (kc + 1 < 32) {
                    const int ko = (kc + 1) * 32;
#pragma unroll
                    for (int mt = 0; mt < 2; ++mt) {
                        pa[mt][0] = *(const float4*)(aptr[mt] + ko);
                        pa[mt][1] = *(const float4*)(aptr[mt] + ko + 4);
                    }
                }
#pragma unroll
                for (int nt = 0; nt < 8; ++nt) {
                    const size_t bo = ((size_t)(nt * 32 + kc) * 64 + l) * 8;
                    short8 bh = *(const short8*)(Bhi + bo);
                    short8 bl = *(const short8*)(Blo + bo);
                    acc[0][nt] = __builtin_amdgcn_mfma_f32_16x16x32_bf16(ahi[0], bh, acc[0][nt], 0, 0, 0);
                    acc[1][nt] = __builtin_amdgcn_mfma_f32_16x16x32_bf16(ahi[1], bh, acc[1][nt], 0, 0, 0);
                    acc[0][nt] = __builtin_amdgcn_mfma_f32_16x16x32_bf16(alo[0], bh, acc[0][nt], 0, 0, 0);
                    acc[1][nt] = __builtin_amdgcn_mfma_f32_16x16x32_bf16(alo[1], bh, acc[1][nt], 0, 0, 0);
                    acc[0][nt] = __builtin_amdgcn_mfma_f32_16x16x32_bf16(ahi[0], bl, acc[0][nt], 0, 0, 0);
                    acc[1][nt] = __builtin_amdgcn_mfma_f32_16x16x32_bf16(ahi[1], bl, acc[1][nt], 0, 0, 0);
                }
            }

            // epilogue: C/D layout col=lane&15, row=quad*4+reg. Permuted store.
#pragma unroll
            for (int nt = 0; nt < 8; ++nt) {
                const int g = nt * 16 + lm;
                if (g < G4) {
                    const int gm = g % 60;
                    const int lane_t = (gm < HH) ? gm : (32 + gm - HH);
                    const int slot = g / 60;
                    const float bb = bias0[g];
#pragma unroll
                    for (int mt = 0; mt < 2; ++mt)
#pragma unroll
                        for (int i = 0; i < 4; ++i) {
                            const size_t row = r0 + mt * 16 + lq * 4 + i;
                            xgp[(row * 64 + lane_t) * 2 + slot] = acc[mt][nt][i] + bb;
                        }
                }
            }
            // per-wave completion: drain this wave's stores, then release-add.
            asm volatile("s_waitcnt vmcnt(0)" ::: "memory");
            if (l == 0)
                __hip_atomic_fetch_add(&cnt[tile >> 4], 1u, __ATOMIC_RELEASE,
                                       __HIP_MEMORY_SCOPE_AGENT);
        }
        return;
    }

    // ======= consumer: 8 batch-pairs per block, two-wave skew per pair =======
    const int wvid = tid >> 6;
    const int pair = wvid >> 1;   // 0..7
    const int role = wvid & 1;    // 0 = layer0 + Wih1 partial, 1 = layer1 finish
    const int l = tid & 63;
    const int b = (blockIdx.x - NPROD) * 8 + pair;
    const int u = l & 31;
    const int half = l >> 5;
    const bool al = (u < HH);
    const int rlo = half * HH + (al ? u : 0);
    const int rhi = 60 + rlo;

    float wa[HH], wb[HH], wc[HH], wd[HH];
    float b1lo = 0.f, b1hi = 0.f;
    if (role == 0) {
#pragma unroll
        for (int j = 0; j < HH; ++j) {
            wa[j] = al ? Whh0[rlo * HH + j] : 0.f;
            wb[j] = al ? Whh0[rhi * HH + j] : 0.f;
            wc[j] = al ? Wih1[rlo * HH + j] : 0.f;
            wd[j] = al ? Wih1[rhi * HH + j] : 0.f;
        }
        b1lo = al ? (bih1[rlo] + bhh1[rlo]) : 0.f;
        b1hi = al ? (bih1[rhi] + bhh1[rhi]) : 0.f;
    } else {
#pragma unroll
        for (int j = 0; j < HH; ++j) {
            wa[j] = al ? Whh1[rlo * HH + j] : 0.f;
            wb[j] = al ? Whh1[rhi * HH + j] : 0.f;
            wc[j] = 0.f; wd[j] = 0.f;
        }
    }

    float hstate = 0.f, cstate = 0.f;
    float hb[HH];
#pragma unroll
    for (int j = 0; j < HH; ++j) hb[j] = 0.f;

    const float2* xgptr = (const float2*)xgp + (size_t)b * 64 + l;
    float2 xq[4];
    unsigned next_g = 0;
    if (role == 0) {
        // wait for group 0 (covers t = 0..31) before the prologue prefetch
        while (__hip_atomic_load(&cnt[0], __ATOMIC_ACQUIRE, __HIP_MEMORY_SCOPE_AGENT) < GDONE)
            __builtin_amdgcn_s_sleep(8);
        next_g = 1;
#pragma unroll
        for (int p = 0; p < 4; ++p) xq[p] = xgptr[(size_t)p * (BB * 64)];
    }

    // t-loop runs to TT inclusive (wave1 lags by 1); unroll x4 keeps xq static.
    for (int t4 = 0; t4 <= TT; t4 += 4) {
#pragma unroll
        for (int q = 0; q < 4; ++q) {
            const int t = t4 + q;
            if (t > TT) break;
            if (role == 0) {
                if (t < TT) {
                    float2 xw = xq[q];
                    const int tn = (t + 4 < TT) ? t + 4 : TT - 1;
                    const unsigned gneed = (unsigned)(tn >> 5);
                    if (gneed >= next_g) {
                        while (__hip_atomic_load(&cnt[gneed], __ATOMIC_ACQUIRE,
                                                 __HIP_MEMORY_SCOPE_AGENT) < GDONE)
                            __builtin_amdgcn_s_sleep(8);
                        next_g = gneed + 1;
                    }
                    xq[q] = xgptr[(size_t)tn * (BB * 64)];

                    // layer-0 gate dot (hb = h1 broadcasts from prev step)
                    float aA = xw.x, aB = 0.f, cA = xw.y, cB = 0.f;
#pragma unroll
                    for (int j = 0; j < HH; j += 2) {
                        aA = fmaf(wa[j], hb[j], aA);
                        cA = fmaf(wb[j], hb[j], cA);
                        aB = fmaf(wa[j + 1], hb[j + 1], aB);
                        cB = fmaf(wb[j + 1], hb[j + 1], cB);
                    }
                    float alo = aA + aB, ahi = cA + cB;
                    float plo = __shfl_xor(alo, 32, 64);
                    float phi = __shfl_xor(ahi, 32, 64);
                    float ipre = half ? plo : alo;
                    float fpre = half ? alo : plo;
                    float gpre = half ? phi : ahi;
                    float opre = half ? ahi : phi;
                    cstate = fsig(fpre) * cstate + fsig(ipre) * ftan(gpre);
                    hstate = fsig(opre) * ftan(cstate);
#pragma unroll
                    for (int j = 0; j < HH; ++j) hb[j] = bcast(hstate, j);

                    // layer-1 input partial: bias1 + Wih1 . h1(t)
                    float zA = b1lo, zB = 0.f, yA = b1hi, yB = 0.f;
#pragma unroll
                    for (int j = 0; j < HH; j += 2) {
                        zA = fmaf(wc[j], hb[j], zA);
                        yA = fmaf(wd[j], hb[j], yA);
                        zB = fmaf(wc[j + 1], hb[j + 1], zB);
                        yB = fmaf(wd[j + 1], hb[j + 1], yB);
                    }
                    pg[pair][t & 1][l] = make_float2(zA + zB, yA + yB);
                }
            } else {
                if (t > 0) {
                    const int s = t - 1;
                    float2 part = pg[pair][s & 1][l];
                    float zA = part.x, zB = 0.f, yA = part.y, yB = 0.f;
#pragma unroll
                    for (int j = 0; j < HH; j += 2) {
                        zA = fmaf(wa[j], hb[j], zA);       // Whh1 . h2(s-1)
                        yA = fmaf(wb[j], hb[j], yA);
                        zB = fmaf(wa[j + 1], hb[j + 1], zB);
                        yB = fmaf(wb[j + 1], hb[j + 1], yB);
                    }
                    float zlo = zA + zB, zhi = yA + yB;
                    float qlo = __shfl_xor(zlo, 32, 64);
                    float qhi = __shfl_xor(zhi, 32, 64);
                    float ipre = half ? qlo : zlo;
                    float fpre = half ? zlo : qlo;
                    float gpre = half ? qhi : zhi;
                    float opre = half ? zhi : qhi;
                    cstate = fsig(fpre) * cstate + fsig(ipre) * ftan(gpre);
                    hstate = fsig(opre) * ftan(cstate);
#pragma unroll
                    for (int j = 0; j < HH; ++j) hb[j] = bcast(hstate, j);
                    if (l < HH) h2buf[((size_t)s * BB + b) * 32 + l] = hstate;
                }
            }
            // LDS-only barrier: xq prefetch + h2 store stay in flight.
            barrier_lds_only();
        }
    }
}

// ---------------------------------------------------------------------------
// Output projection: out[t,b] = h2buf[t,b,:] . Wout + bout
__global__ __launch_bounds__(256) void out_proj(
    const float* __restrict__ h2buf, const float* __restrict__ Wout,
    const float* __restrict__ bout, float* __restrict__ out) {
    __shared__ float wos[32];
    if (threadIdx.x < 32)
        wos[threadIdx.x] = (threadIdx.x < HH) ? Wout[threadIdx.x] : 0.0f;
    __syncthreads();
    const int idx = blockIdx.x * 256 + threadIdx.x;   // 0..65535
    const float4* hp = (const float4*)(h2buf + (size_t)idx * 32);
    float s0 = 0.f, s1 = 0.f;
#pragma unroll
    for (int q = 0; q < 8; ++q) {
        float4 h = hp[q];
        s0 = fmaf(h.x, wos[q * 4 + 0], s0);
        s1 = fmaf(h.y, wos[q * 4 + 1], s1);
        s0 = fmaf(h.z, wos[q * 4 + 2], s0);
        s1 = fmaf(h.w, wos[q * 4 + 3], s1);
    }
    out[idx] = s0 + s1 + bout[0];
}

// ---------------------------------------------------------------------------
extern "C" void kernel_launch(void* const* d_in, const int* in_sizes, int n_in,
                              void* d_out, int out_size, void* d_ws, size_t ws_size,
                              hipStream_t stream) {
    const float* x    = (const float*)d_in[0];
    const float* Wih0 = (const float*)d_in[1];
    const float* Whh0 = (const float*)d_in[2];
    const float* bih0 = (const float*)d_in[3];
    const float* bhh0 = (const float*)d_in[4];
    const float* Wih1 = (const float*)d_in[5];
    const float* Whh1 = (const float*)d_in[6];
    const float* bih1 = (const float*)d_in[7];
    const float* bhh1 = (const float*)d_in[8];
    const float* Wout = (const float*)d_in[9];
    const float* bout = (const float*)d_in[10];
    float* out = (float*)d_out;

    char* ws = (char*)d_ws;
    unsigned short* Bhi = (unsigned short*)ws;                 // 256 KB
    unsigned short* Blo = (unsigned short*)(ws + 262144);      // 256 KB
    float* bias0 = (float*)(ws + 524288);                      // 512 B
    unsigned* cnt = (unsigned*)(ws + 524800);                  // 128 B flags
    float* xgp   = (float*)(ws + 1024 * 1024);                 // 33.55 MB
    float* h2buf = (float*)(ws + 36 * 1024 * 1024);            // 8.39 MB

    prep_kernel<<<64, 256, 0, stream>>>(Wih0, bih0, bhh0, Bhi, Blo, bias0, cnt);
    fused_fwd<<<NPROD + NCBLK, 1024, 0, stream>>>(x, Bhi, Blo, bias0, xgp,
                                                  Whh0, Wih1, Whh1, bih1, bhh1,
                                                  h2buf, cnt);
    out_proj<<<256, 256, 0, stream>>>(h2buf, Wout, bout, out);
}

// Round 5
// 1077.564 us; speedup vs baseline: 5.8445x; 5.8445x over previous
//
#include <hip/hip_runtime.h>
#include <hip/hip_bf16.h>
#include <cstdint>

#define TT 1024
#define BB 64
#define DD 1024
#define HH 30
#define G4 120

#define NPROD 64    // producer blocks (GEMM), t-striped rounds
#define NROUND 8    // tiles per producer block
#define NCONS 16    // consumer blocks (4 waves each, 1 batch element per wave)
#define GBLK 16     // tiles per flag group => 32 timesteps per group
#define NGRP 32     // number of flag groups

typedef __attribute__((ext_vector_type(8))) short short8;
typedef __attribute__((ext_vector_type(4))) float float4v;

// ---------------------------------------------------------------------------
__device__ __forceinline__ float frcp(float x) { return __builtin_amdgcn_rcpf(x); }
__device__ __forceinline__ float fsig(float x) { return frcp(1.0f + __expf(-x)); }
__device__ __forceinline__ float ftan(float x) {
    return 2.0f * frcp(1.0f + __expf(-2.0f * x)) - 1.0f;
}
__device__ __forceinline__ float bcast(float v, int l) {
    return __int_as_float(__builtin_amdgcn_readlane(__float_as_int(v), l));
}
__device__ __forceinline__ unsigned short bf16_rne(float f) {
    unsigned u = __float_as_uint(f);
    return (unsigned short)((u + 0x7FFFu + ((u >> 16) & 1u)) >> 16);
}

// ---------------------------------------------------------------------------
// Prep: pack W_ih0 into MFMA B-fragment order (split bf16 hi/lo), combine
// layer-0 biases, zero the producer-consumer flags.
__global__ void prep_kernel(const float* __restrict__ Wih0,
                            const float* __restrict__ bih0,
                            const float* __restrict__ bhh0,
                            unsigned short* __restrict__ Bhi,
                            unsigned short* __restrict__ Blo,
                            float* __restrict__ bias0,
                            unsigned* __restrict__ cnt) {
    int idx = blockIdx.x * 256 + threadIdx.x;   // 0..16383
    int l  = idx & 63;
    int kc = (idx >> 6) & 31;
    int nt = idx >> 11;
    int n = nt * 16 + (l & 15);
    int kb = kc * 32 + (l >> 4) * 8;
    size_t o = (size_t)idx * 8;
#pragma unroll
    for (int j = 0; j < 8; ++j) {
        float wv = (n < G4) ? Wih0[(size_t)n * DD + kb + j] : 0.0f;
        unsigned short hi = bf16_rne(wv);
        float fhi = __uint_as_float((unsigned)hi << 16);
        unsigned short lo = bf16_rne(wv - fhi);
        Bhi[o + j] = hi;
        Blo[o + j] = lo;
    }
    if (idx < 128) bias0[idx] = (idx < G4) ? (bih0[idx] + bhh0[idx]) : 0.0f;
    if (idx < NGRP) cnt[idx] = 0u;
}

// ---------------------------------------------------------------------------
// One pipelined recurrence step for one batch element, single wave.
// At entry: h1b = bcast(h1(t-1)), h2b = bcast(h2(t-2)), c1 = c1(t-1),
// c2 = c2(t-2). Layer-1 (for s = t-1) and layer-0 (for t) are INDEPENDENT
// chains — both read only the pre-update broadcasts — so the compiler can
// interleave them (the two-wave skew's overlap without barrier/LDS).
template<int Q, bool DO_L1, bool DO_L0>
__device__ __forceinline__ void lstm_step(
    const int t, const int half, const int l, const int b,
    const float (&wa0)[HH], const float (&wb0)[HH],
    const float (&wc1)[HH], const float (&wd1)[HH],
    const float (&we1)[HH], const float (&wf1)[HH],
    const float b1lo, const float b1hi,
    float (&h1b)[HH], float (&h2b)[HH],
    float& c1, float& c2, float2 (&xq)[4],
    const float2* __restrict__ xgptr,
    unsigned& next_g, const unsigned* __restrict__ cnt,
    float* __restrict__ h2buf) {

    // ---- layer-1 gate dots for s = t-1 (reads old h1b, h2b) ----
    float zA = 0.f, zB = 0.f, yA = 0.f, yB = 0.f;
    if (DO_L1) {
        zA = b1lo; yA = b1hi;
#pragma unroll
        for (int j = 0; j < HH; j += 2) {
            zA = fmaf(wc1[j], h1b[j], zA);
            yA = fmaf(wd1[j], h1b[j], yA);
            zB = fmaf(wc1[j + 1], h1b[j + 1], zB);
            yB = fmaf(wd1[j + 1], h1b[j + 1], yB);
        }
#pragma unroll
        for (int j = 0; j < HH; j += 2) {
            zA = fmaf(we1[j], h2b[j], zA);
            yA = fmaf(wf1[j], h2b[j], yA);
            zB = fmaf(we1[j + 1], h2b[j + 1], zB);
            yB = fmaf(wf1[j + 1], h2b[j + 1], yB);
        }
    }

    // ---- layer-0 for t (reads old h1b) ----
    float h1new = 0.f;
    if (DO_L0) {
        float2 xw = xq[Q];
        const int tn = (t + 4 < TT) ? t + 4 : TT - 1;
        const unsigned gneed = (unsigned)(tn >> 5);
        if (gneed >= next_g) {
            while (__hip_atomic_load(&cnt[gneed], __ATOMIC_ACQUIRE,
                                     __HIP_MEMORY_SCOPE_AGENT) < GBLK)
                __builtin_amdgcn_s_sleep(8);
            next_g = gneed + 1;
        }
        xq[Q] = xgptr[(size_t)tn * (BB * 64)];

        float aA = xw.x, aB = 0.f, cA = xw.y, cB = 0.f;
#pragma unroll
        for (int j = 0; j < HH; j += 2) {
            aA = fmaf(wa0[j], h1b[j], aA);
            cA = fmaf(wb0[j], h1b[j], cA);
            aB = fmaf(wa0[j + 1], h1b[j + 1], aB);
            cB = fmaf(wb0[j + 1], h1b[j + 1], cB);
        }
        float alo = aA + aB, ahi = cA + cB;
        float plo = __shfl_xor(alo, 32, 64);
        float phi = __shfl_xor(ahi, 32, 64);
        float ipre = half ? plo : alo;
        float fpre = half ? alo : plo;
        float gpre = half ? phi : ahi;
        float opre = half ? ahi : phi;
        c1 = fsig(fpre) * c1 + fsig(ipre) * ftan(gpre);
        h1new = fsig(opre) * ftan(c1);
    }

    // ---- layer-1 activations + h2 store + h2b update ----
    if (DO_L1) {
        float zlo = zA + zB, zhi = yA + yB;
        float qlo = __shfl_xor(zlo, 32, 64);
        float qhi = __shfl_xor(zhi, 32, 64);
        float ipre = half ? qlo : zlo;
        float fpre = half ? zlo : qlo;
        float gpre = half ? qhi : zhi;
        float opre = half ? zhi : qhi;
        c2 = fsig(fpre) * c2 + fsig(ipre) * ftan(gpre);
        float h2new = fsig(opre) * ftan(c2);
        if (l < HH) h2buf[((size_t)(t - 1) * BB + b) * 32 + l] = h2new;
#pragma unroll
        for (int j = 0; j < HH; ++j) h2b[j] = bcast(h2new, j);
    }
    // ---- h1b update (after all readers of old h1b) ----
    if (DO_L0) {
#pragma unroll
        for (int j = 0; j < HH; ++j) h1b[j] = bcast(h1new, j);
    }
}

// ---------------------------------------------------------------------------
// Fused producer-consumer kernel.
//  blocks [0, NPROD): GEMM producers, t-striped rounds, release-add a flag
//      per tile (16 tiles = 32 timesteps). Identical to the round-2 version.
//  blocks [NPROD, NPROD+NCONS): consumers, 4 waves each; ONE wave runs both
//      LSTM layers for one batch element, software-pipelined (layer-1 lags
//      one step), no barriers, no LDS.
// No deadlock: producers never wait; consumers wait only on producers.
__global__ __launch_bounds__(256) void fused_fwd(
    const float* __restrict__ x, const unsigned short* __restrict__ Bhi,
    const unsigned short* __restrict__ Blo, const float* __restrict__ bias0,
    float* __restrict__ xgp, const float* __restrict__ Whh0,
    const float* __restrict__ Wih1, const float* __restrict__ Whh1,
    const float* __restrict__ bih1, const float* __restrict__ bhh1,
    float* __restrict__ h2buf, unsigned* __restrict__ cnt) {

    const int tid = threadIdx.x;

    if (blockIdx.x < NPROD) {
        // ================= producer: xg = x @ Wih0^T (+bias) =================
        const int pb = blockIdx.x;
        const int w = tid >> 6;
        const int l = tid & 63;
        const int lm = l & 15, lq = l >> 4;

        for (int r = 0; r < NROUND; ++r) {
            const int tile = r * NPROD + pb;          // 0..511, t-pair index
            const int r0 = tile * 128 + w * 32;

            float4v acc[2][8];
#pragma unroll
            for (int mt = 0; mt < 2; ++mt)
#pragma unroll
                for (int nt = 0; nt < 8; ++nt) acc[mt][nt] = (float4v)0.0f;

            const float* aptr[2];
            aptr[0] = x + (size_t)(r0 + lm) * DD + lq * 8;
            aptr[1] = x + (size_t)(r0 + 16 + lm) * DD + lq * 8;

            float4 pa[2][2];
#pragma unroll
            for (int mt = 0; mt < 2; ++mt) {
                pa[mt][0] = *(const float4*)(aptr[mt]);
                pa[mt][1] = *(const float4*)(aptr[mt] + 4);
            }

            for (int kc = 0; kc < 32; ++kc) {
                short8 ahi[2], alo[2];
#pragma unroll
                for (int mt = 0; mt < 2; ++mt) {
                    float f[8] = {pa[mt][0].x, pa[mt][0].y, pa[mt][0].z, pa[mt][0].w,
                                  pa[mt][1].x, pa[mt][1].y, pa[mt][1].z, pa[mt][1].w};
#pragma unroll
                    for (int i = 0; i < 8; ++i) {
                        unsigned ub = __float_as_uint(f[i]);
                        ahi[mt][i] = (short)(ub >> 16);
                        float fr = f[i] - __uint_as_float(ub & 0xFFFF0000u);
                        alo[mt][i] = (short)(__float_as_uint(fr) >> 16);
                    }
                }
                if (kc + 1 < 32) {
                    const int ko = (kc + 1) * 32;
#pragma unroll
                    for (int mt = 0; mt < 2; ++mt) {
                        pa[mt][0] = *(const float4*)(aptr[mt] + ko);
                        pa[mt][1] = *(const float4*)(aptr[mt] + ko + 4);
                    }
                }
#pragma unroll
                for (int nt = 0; nt < 8; ++nt) {
                    const size_t bo = ((size_t)(nt * 32 + kc) * 64 + l) * 8;
                    short8 bh = *(const short8*)(Bhi + bo);
                    short8 bl = *(const short8*)(Blo + bo);
                    acc[0][nt] = __builtin_amdgcn_mfma_f32_16x16x32_bf16(ahi[0], bh, acc[0][nt], 0, 0, 0);
                    acc[1][nt] = __builtin_amdgcn_mfma_f32_16x16x32_bf16(ahi[1], bh, acc[1][nt], 0, 0, 0);
                    acc[0][nt] = __builtin_amdgcn_mfma_f32_16x16x32_bf16(alo[0], bh, acc[0][nt], 0, 0, 0);
                    acc[1][nt] = __builtin_amdgcn_mfma_f32_16x16x32_bf16(alo[1], bh, acc[1][nt], 0, 0, 0);
                    acc[0][nt] = __builtin_amdgcn_mfma_f32_16x16x32_bf16(ahi[0], bl, acc[0][nt], 0, 0, 0);
                    acc[1][nt] = __builtin_amdgcn_mfma_f32_16x16x32_bf16(ahi[1], bl, acc[1][nt], 0, 0, 0);
                }
            }

            // epilogue: C/D layout col=lane&15, row=quad*4+reg. Permuted store.
#pragma unroll
            for (int nt = 0; nt < 8; ++nt) {
                const int g = nt * 16 + lm;
                if (g < G4) {
                    const int gm = g % 60;
                    const int lane_t = (gm < HH) ? gm : (32 + gm - HH);
                    const int slot = g / 60;
                    const float bb = bias0[g];
#pragma unroll
                    for (int mt = 0; mt < 2; ++mt)
#pragma unroll
                        for (int i = 0; i < 4; ++i) {
                            const size_t row = r0 + mt * 16 + lq * 4 + i;
                            xgp[(row * 64 + lane_t) * 2 + slot] = acc[mt][nt][i] + bb;
                        }
                }
            }
            __syncthreads();   // full drain: stores done before the release add
            if (tid == 0) {
                __threadfence();
                __hip_atomic_fetch_add(&cnt[tile >> 4], 1u, __ATOMIC_RELEASE,
                                       __HIP_MEMORY_SCOPE_AGENT);
            }
        }
        return;
    }

    // ========== consumer: both layers in one wave, software-pipelined ==========
    const int wv = tid >> 6;
    const int l = tid & 63;
    const int b = (blockIdx.x - NPROD) * 4 + wv;   // one batch element per wave
    const int u = l & 31;
    const int half = l >> 5;
    const bool al = (u < HH);
    const int rlo = half * HH + (al ? u : 0);
    const int rhi = 60 + rlo;

    float wa0[HH], wb0[HH], wc1[HH], wd1[HH], we1[HH], wf1[HH];
#pragma unroll
    for (int j = 0; j < HH; ++j) {
        wa0[j] = al ? Whh0[rlo * HH + j] : 0.f;
        wb0[j] = al ? Whh0[rhi * HH + j] : 0.f;
        wc1[j] = al ? Wih1[rlo * HH + j] : 0.f;
        wd1[j] = al ? Wih1[rhi * HH + j] : 0.f;
        we1[j] = al ? Whh1[rlo * HH + j] : 0.f;
        wf1[j] = al ? Whh1[rhi * HH + j] : 0.f;
    }
    const float b1lo = al ? (bih1[rlo] + bhh1[rlo]) : 0.f;
    const float b1hi = al ? (bih1[rhi] + bhh1[rhi]) : 0.f;

    float c1 = 0.f, c2 = 0.f;
    float h1b[HH], h2b[HH];
#pragma unroll
    for (int j = 0; j < HH; ++j) { h1b[j] = 0.f; h2b[j] = 0.f; }

    const float2* xgptr = (const float2*)xgp + (size_t)b * 64 + l;
    float2 xq[4];
    // wait for group 0 (covers t = 0..31) before the prologue prefetch
    while (__hip_atomic_load(&cnt[0], __ATOMIC_ACQUIRE, __HIP_MEMORY_SCOPE_AGENT) < GBLK)
        __builtin_amdgcn_s_sleep(8);
    unsigned next_g = 1;
#pragma unroll
    for (int p = 0; p < 4; ++p) xq[p] = xgptr[(size_t)p * (BB * 64)];

#define ARGS half, l, b, wa0, wb0, wc1, wd1, we1, wf1, b1lo, b1hi, \
             h1b, h2b, c1, c2, xq, xgptr, next_g, cnt, h2buf

    // t = 0: layer-0 only (h2(-1) undefined)
    lstm_step<0, false, true>(0, ARGS);
    // main: t = 1 .. TT-7+3 = 1020, branch-free, 4x unrolled (static xq idx)
    for (int t4 = 1; t4 <= TT - 7; t4 += 4) {
        lstm_step<1, true, true>(t4 + 0, ARGS);
        lstm_step<2, true, true>(t4 + 1, ARGS);
        lstm_step<3, true, true>(t4 + 2, ARGS);
        lstm_step<0, true, true>(t4 + 3, ARGS);
    }
    // peeled: t = 1021, 1022, 1023
    lstm_step<1, true, true>(TT - 3, ARGS);
    lstm_step<2, true, true>(TT - 2, ARGS);
    lstm_step<3, true, true>(TT - 1, ARGS);
    // tail: t = TT, layer-1 only (finishes s = TT-1)
    lstm_step<0, true, false>(TT, ARGS);
#undef ARGS
}

// ---------------------------------------------------------------------------
// Output projection: out[t,b] = h2buf[t,b,:] . Wout + bout
__global__ __launch_bounds__(256) void out_proj(
    const float* __restrict__ h2buf, const float* __restrict__ Wout,
    const float* __restrict__ bout, float* __restrict__ out) {
    __shared__ float wos[32];
    if (threadIdx.x < 32)
        wos[threadIdx.x] = (threadIdx.x < HH) ? Wout[threadIdx.x] : 0.0f;
    __syncthreads();
    const int idx = blockIdx.x * 256 + threadIdx.x;   // 0..65535
    const float4* hp = (const float4*)(h2buf + (size_t)idx * 32);
    float s0 = 0.f, s1 = 0.f;
#pragma unroll
    for (int q = 0; q < 8; ++q) {
        float4 h = hp[q];
        s0 = fmaf(h.x, wos[q * 4 + 0], s0);
        s1 = fmaf(h.y, wos[q * 4 + 1], s1);
        s0 = fmaf(h.z, wos[q * 4 + 2], s0);
        s1 = fmaf(h.w, wos[q * 4 + 3], s1);
    }
    out[idx] = s0 + s1 + bout[0];
}

// ---------------------------------------------------------------------------
extern "C" void kernel_launch(void* const* d_in, const int* in_sizes, int n_in,
                              void* d_out, int out_size, void* d_ws, size_t ws_size,
                              hipStream_t stream) {
    const float* x    = (const float*)d_in[0];
    const float* Wih0 = (const float*)d_in[1];
    const float* Whh0 = (const float*)d_in[2];
    const float* bih0 = (const float*)d_in[3];
    const float* bhh0 = (const float*)d_in[4];
    const float* Wih1 = (const float*)d_in[5];
    const float* Whh1 = (const float*)d_in[6];
    const float* bih1 = (const float*)d_in[7];
    const float* bhh1 = (const float*)d_in[8];
    const float* Wout = (const float*)d_in[9];
    const float* bout = (const float*)d_in[10];
    float* out = (float*)d_out;

    char* ws = (char*)d_ws;
    unsigned short* Bhi = (unsigned short*)ws;                 // 256 KB
    unsigned short* Blo = (unsigned short*)(ws + 262144);      // 256 KB
    float* bias0 = (float*)(ws + 524288);                      // 512 B
    unsigned* cnt = (unsigned*)(ws + 524800);                  // 128 B flags
    float* xgp   = (float*)(ws + 1024 * 1024);                 // 33.55 MB
    float* h2buf = (float*)(ws + 36 * 1024 * 1024);            // 8.39 MB

    prep_kernel<<<64, 256, 0, stream>>>(Wih0, bih0, bhh0, Bhi, Blo, bias0, cnt);
    fused_fwd<<<NPROD + NCONS, 256, 0, stream>>>(x, Bhi, Blo, bias0, xgp,
                                                 Whh0, Wih1, Whh1, bih1, bhh1,
                                                 h2buf, cnt);
    out_proj<<<256, 256, 0, stream>>>(h2buf, Wout, bout, out);
}